// Round 3
// baseline (930.826 us; speedup 1.0000x reference)
//
#include <hip/hip_runtime.h>
#include <stdint.h>

#define NB 4
#define NC 64
#define NH 192
#define NW 192

typedef __attribute__((ext_vector_type(8))) short bf16x8;
typedef __attribute__((ext_vector_type(4))) float f32x4;
typedef unsigned short u16;
typedef unsigned int u32;

__device__ inline float bf2f(u16 x){ u32 u = ((u32)x) << 16; return __builtin_bit_cast(float, u); }
__device__ inline u16 f2bf(float f){ u32 u = __builtin_bit_cast(u32, f); u32 r = u + 0x7fffu + ((u >> 16) & 1u); return (u16)(r >> 16); }

// ---------------- weight transform: f32 OIHW [co][ci][ky][kx] -> bf16 [r][co][ci] ----------------
__global__ void wxform_k(const float* __restrict__ w0, const float* __restrict__ w1,
                         const float* __restrict__ w2, const float* __restrict__ w3,
                         const float* __restrict__ w4, u16* __restrict__ out){
  int idx = blockIdx.x * 256 + threadIdx.x;
  if (idx >= 5 * 36864) return;
  int t = idx / 36864, e = idx % 36864;
  int r = e >> 12, rem = e & 4095, co = rem >> 6, ci = rem & 63;
  const float* src = (t == 0) ? w0 : (t == 1) ? w1 : (t == 2) ? w2 : (t == 3) ? w3 : w4;
  out[idx] = f2bf(src[co * 576 + ci * 9 + r]);
}

// ---------------- f32 NCHW -> bf16 NHWC ----------------
__global__ __launch_bounds__(192) void nchw2nhwc_k(const float* __restrict__ in, u16* __restrict__ out){
  int bh = blockIdx.x; int b = bh / NH, h = bh % NH;
  int w = threadIdx.x;
  u16 v[64];
  const float* p = in + ((size_t)b * NC * NH + h) * NW + w;   // in[b][c][h][w]
#pragma unroll
  for (int c = 0; c < 64; ++c) v[c] = f2bf(p[(size_t)c * NH * NW]);
  uint4* q4 = (uint4*)(out + ((size_t)bh * NW + w) * NC);
#pragma unroll
  for (int i = 0; i < 8; ++i){
    uint4 t;
    t.x = (u32)v[i*8+0] | ((u32)v[i*8+1] << 16);
    t.y = (u32)v[i*8+2] | ((u32)v[i*8+3] << 16);
    t.z = (u32)v[i*8+4] | ((u32)v[i*8+5] << 16);
    t.w = (u32)v[i*8+6] | ((u32)v[i*8+7] << 16);
    q4[i] = t;
  }
}

// ---------------- bf16 NHWC -> f32 NCHW ----------------
__global__ __launch_bounds__(192) void nhwc2nchw_k(const u16* __restrict__ in, float* __restrict__ out){
  int bh = blockIdx.x; int b = bh / NH, h = bh % NH;
  int w = threadIdx.x;
  const uint4* q4 = (const uint4*)(in + ((size_t)bh * NW + w) * NC);
  u16 v[64];
#pragma unroll
  for (int i = 0; i < 8; ++i){
    uint4 t = q4[i];
    v[i*8+0] = (u16)(t.x & 0xffff); v[i*8+1] = (u16)(t.x >> 16);
    v[i*8+2] = (u16)(t.y & 0xffff); v[i*8+3] = (u16)(t.y >> 16);
    v[i*8+4] = (u16)(t.z & 0xffff); v[i*8+5] = (u16)(t.z >> 16);
    v[i*8+6] = (u16)(t.w & 0xffff); v[i*8+7] = (u16)(t.w >> 16);
  }
  float* p = out + ((size_t)b * NC * NH + h) * NW + w;
#pragma unroll
  for (int c = 0; c < 64; ++c) p[(size_t)c * NH * NW] = bf2f(v[c]);
}

// ---------------- conv3x3 (NHWC bf16, implicit GEMM, 9-shift) ----------------
// out[b][h][x][co] = bias[co] + sum_{ky,kx,ci} Wt[r][co][ci] * in[b][h+ky-1][x+kx-1][ci]  (+relu, +skip)
__global__ __launch_bounds__(256) void conv3_k(const u16* __restrict__ in, const u16* __restrict__ wt,
    const float* __restrict__ bias, const u16* __restrict__ skip, u16* __restrict__ out, int relu){
  __shared__ __align__(16) u16 xl[3 * 194 * 64];
  int bh = blockIdx.x; int b = bh / NH, h = bh % NH;
  int tid = threadIdx.x;
  const size_t rowbase = (size_t)bh * (NW * NC);
  // stage 3 input rows, x index = w+1 (zero pad x=0,193)
  for (int r = 0; r < 3; ++r){
    int hh = h - 1 + r;
    uint4* dst = (uint4*)&xl[r * 194 * 64];
    if (hh >= 0 && hh < NH){
      const uint4* src = (const uint4*)(in + ((size_t)(b * NH + hh)) * (NW * NC));
      for (int i = tid; i < 1536; i += 256) dst[i + 8] = src[i];
      if (tid < 8) dst[tid] = make_uint4(0,0,0,0);
      else if (tid < 16) dst[1544 + tid - 8] = make_uint4(0,0,0,0);
    } else {
      uint4 z = make_uint4(0,0,0,0);
      for (int i = tid; i < 1552; i += 256) dst[i] = z;
    }
  }
  __syncthreads();
  int wv = tid >> 6, lane = tid & 63, l15 = lane & 15, qd = lane >> 4;
  f32x4 acc[4][3];
#pragma unroll
  for (int mt = 0; mt < 4; ++mt)
#pragma unroll
    for (int nt = 0; nt < 3; ++nt) acc[mt][nt] = (f32x4){0.f,0.f,0.f,0.f};

#pragma unroll
  for (int r = 0; r < 9; ++r){
    const int ky = r / 3, kx = r % 3;
#pragma unroll
    for (int ks = 0; ks < 2; ++ks){
      int ci = ks * 32 + qd * 8;
      bf16x8 a[4];
      const u16* wp = wt + r * 4096 + ci;
#pragma unroll
      for (int mt = 0; mt < 4; ++mt) a[mt] = *(const bf16x8*)(wp + (mt * 16 + l15) * 64);
#pragma unroll
      for (int nt = 0; nt < 3; ++nt){
        int x = wv * 48 + nt * 16 + l15 + kx;   // lds x index (input w = x-1)
        bf16x8 bfr = *(const bf16x8*)&xl[(ky * 194 + x) * 64 + ci];
#pragma unroll
        for (int mt = 0; mt < 4; ++mt)
          acc[mt][nt] = __builtin_amdgcn_mfma_f32_16x16x32_bf16(a[mt], bfr, acc[mt][nt], 0, 0, 0);
      }
    }
  }
#pragma unroll
  for (int mt = 0; mt < 4; ++mt){
    int co0 = mt * 16 + qd * 4;
    float4 bb = *(const float4*)(bias + co0);
#pragma unroll
    for (int nt = 0; nt < 3; ++nt){
      int x = wv * 48 + nt * 16 + l15;
      size_t o = rowbase + (size_t)x * NC + co0;
      float v0 = acc[mt][nt][0] + bb.x, v1 = acc[mt][nt][1] + bb.y;
      float v2 = acc[mt][nt][2] + bb.z, v3 = acc[mt][nt][3] + bb.w;
      if (relu){ v0 = fmaxf(v0,0.f); v1 = fmaxf(v1,0.f); v2 = fmaxf(v2,0.f); v3 = fmaxf(v3,0.f); }
      if (skip){
        uint2 ss = *(const uint2*)(skip + o);
        v0 += bf2f((u16)(ss.x & 0xffff)); v1 += bf2f((u16)(ss.x >> 16));
        v2 += bf2f((u16)(ss.y & 0xffff)); v3 += bf2f((u16)(ss.y >> 16));
      }
      uint2 st;
      st.x = (u32)f2bf(v0) | ((u32)f2bf(v1) << 16);
      st.y = (u32)f2bf(v2) | ((u32)f2bf(v3) << 16);
      *(uint2*)(out + o) = st;
    }
  }
}

// ---------------- attention stage ----------------
// P = softmax_rows(Qrow · Krow^T)   [192x192], per (b,h)
// outA = Yrow + P  · Xrow   (apply)     -> NHWC bf16
// outB = Xrow + P^T· Yrow   (apply_T)   -> NHWC bf16
__global__ __launch_bounds__(256) void attn_k(const u16* __restrict__ Q, const u16* __restrict__ K,
    const u16* __restrict__ X, const u16* __restrict__ Y,
    u16* __restrict__ outA, u16* __restrict__ outB){
  __shared__ __align__(16) u16 P [192 * 200];
  __shared__ __align__(16) u16 Xt[64 * 200];
  __shared__ __align__(16) u16 Yt[64 * 200];
  int bh = blockIdx.x;
  int tid = threadIdx.x;
  size_t rowo = (size_t)bh * (NW * NC);
  const u16* Qr = Q + rowo; const u16* Kr = K + rowo;
  const u16* Xr = X + rowo; const u16* Yr = Y + rowo;
  // stage X,Y transposed: Xt[c][w]
  for (int e = tid; e < NW * NC; e += 256){
    int w = e >> 6, c = e & 63;
    Xt[c * 200 + w] = Xr[e];
    Yt[c * 200 + w] = Yr[e];
  }
  int wv = tid >> 6, lane = tid & 63, l15 = lane & 15, qd = lane >> 4;
  // ---- phase 1: S = Q K^T, softmax over v, P -> LDS ----
#pragma unroll 1
  for (int mi = 0; mi < 3; ++mi){
    int mt = wv * 3 + mi;
    f32x4 s[12];
#pragma unroll
    for (int nt = 0; nt < 12; ++nt) s[nt] = (f32x4){0,0,0,0};
#pragma unroll
    for (int ks = 0; ks < 2; ++ks){
      bf16x8 aq = *(const bf16x8*)(Qr + (mt * 16 + l15) * 64 + ks * 32 + qd * 8);
#pragma unroll
      for (int nt = 0; nt < 12; ++nt){
        bf16x8 bk = *(const bf16x8*)(Kr + (nt * 16 + l15) * 64 + ks * 32 + qd * 8);
        s[nt] = __builtin_amdgcn_mfma_f32_16x16x32_bf16(aq, bk, s[nt], 0, 0, 0);
      }
    }
#pragma unroll
    for (int rg = 0; rg < 4; ++rg){
      float mx = -1e30f;
#pragma unroll
      for (int nt = 0; nt < 12; ++nt) mx = fmaxf(mx, s[nt][rg]);
      mx = fmaxf(mx, __shfl_xor(mx, 1));
      mx = fmaxf(mx, __shfl_xor(mx, 2));
      mx = fmaxf(mx, __shfl_xor(mx, 4));
      mx = fmaxf(mx, __shfl_xor(mx, 8));
      float sum = 0.f;
#pragma unroll
      for (int nt = 0; nt < 12; ++nt){ float ev = __expf(s[nt][rg] - mx); s[nt][rg] = ev; sum += ev; }
      sum += __shfl_xor(sum, 1);
      sum += __shfl_xor(sum, 2);
      sum += __shfl_xor(sum, 4);
      sum += __shfl_xor(sum, 8);
      float inv = 1.f / sum;
      int w = mt * 16 + qd * 4 + rg;
#pragma unroll
      for (int nt = 0; nt < 12; ++nt)
        P[w * 200 + nt * 16 + l15] = f2bf(s[nt][rg] * inv);
    }
  }
  __syncthreads();
  // ---- phase 2: outA = Y + P X ; outB = X + P^T Y ----
#pragma unroll 1
  for (int mi = 0; mi < 3; ++mi){
    int mt = wv * 3 + mi;
    f32x4 aA[4], aB[4];
#pragma unroll
    for (int nt = 0; nt < 4; ++nt){ aA[nt] = (f32x4){0,0,0,0}; aB[nt] = (f32x4){0,0,0,0}; }
#pragma unroll 1
    for (int ks = 0; ks < 6; ++ks){
      int v0 = ks * 32 + qd * 8;
      bf16x8 ap = *(const bf16x8*)&P[(mt * 16 + l15) * 200 + v0];
      bf16x8 apt;
#pragma unroll
      for (int j = 0; j < 8; ++j) apt[j] = (short)P[(v0 + j) * 200 + mt * 16 + l15];
#pragma unroll
      for (int nt = 0; nt < 4; ++nt){
        bf16x8 bx = *(const bf16x8*)&Xt[(nt * 16 + l15) * 200 + v0];
        bf16x8 by = *(const bf16x8*)&Yt[(nt * 16 + l15) * 200 + v0];
        aA[nt] = __builtin_amdgcn_mfma_f32_16x16x32_bf16(ap,  bx, aA[nt], 0, 0, 0);
        aB[nt] = __builtin_amdgcn_mfma_f32_16x16x32_bf16(apt, by, aB[nt], 0, 0, 0);
      }
    }
    int w0 = mt * 16 + qd * 4;
#pragma unroll
    for (int nt = 0; nt < 4; ++nt){
      int c = nt * 16 + l15;
#pragma unroll
      for (int rg = 0; rg < 4; ++rg){
        float va = aA[nt][rg] + bf2f(Yt[c * 200 + w0 + rg]);
        float vb = aB[nt][rg] + bf2f(Xt[c * 200 + w0 + rg]);
        outA[rowo + (size_t)(w0 + rg) * 64 + c] = f2bf(va);
        outB[rowo + (size_t)(w0 + rg) * 64 + c] = f2bf(vb);
      }
    }
  }
}

extern "C" void kernel_launch(void* const* d_in, const int* in_sizes, int n_in,
                              void* d_out, int out_size, void* d_ws, size_t ws_size,
                              hipStream_t stream){
  const float* low1 = (const float*)d_in[0];
  const float* low2 = (const float*)d_in[1];
  const float* b11 = (const float*)d_in[3];
  const float* b12 = (const float*)d_in[5];
  const float* b21 = (const float*)d_in[7];
  const float* b22 = (const float*)d_in[9];
  const float* bcv = (const float*)d_in[11];
  const size_t BUF = (size_t)NB * NH * NW * NC;   // 9437184 elements
  // ws (bf16): WT | s1 | s2   -> peak 38.1 MB
  u16* WT = (u16*)d_ws;               // 5*36864 = 184320 els
  u16* s1 = WT + 184320;              // Q1 -> F2 -> left  NHWC
  u16* s2 = s1 + BUF;                 // K1 -> F1 -> right NHWC
  // d_out (f32, 2*BUF floats = 75.5 MB) doubles as 4 bf16 NHWC scratch slots
  u16* o1 = (u16*)d_out;              // L1T -> Q2
  u16* o2 = o1 + BUF;                 // L2T -> K2
  u16* o3 = o1 + 2 * BUF;             // conv temp (relu stage)
  u16* o4 = o1 + 3 * BUF;             // conv temp (csm stage)
  float* outL = (float*)d_out;        // final left  (NCHW f32)
  float* outR = outL + BUF;           // final right (NCHW f32)

  wxform_k<<<dim3(720), dim3(256), 0, stream>>>(
      (const float*)d_in[2], (const float*)d_in[4], (const float*)d_in[6],
      (const float*)d_in[8], (const float*)d_in[10], WT);
  nchw2nhwc_k<<<dim3(NB * NH), dim3(192), 0, stream>>>(low1, o1);   // L1T
  nchw2nhwc_k<<<dim3(NB * NH), dim3(192), 0, stream>>>(low2, o2);   // L2T

#define CONV(in_, wti, bias_, skip_, out_, relu_) \
  conv3_k<<<dim3(NB * NH), dim3(256), 0, stream>>>(in_, WT + (wti) * 36864, bias_, skip_, out_, relu_)

  // fe1 @ low1 -> Q1 (s1)
  CONV(o1, 0, b11, (const u16*)nullptr, o3, 1);
  CONV(o3, 1, b12, o1, o4, 0);
  CONV(o4, 4, bcv, (const u16*)nullptr, s1, 0);
  // fe1 @ low2 -> K1 (s2)
  CONV(o2, 0, b11, (const u16*)nullptr, o3, 1);
  CONV(o3, 1, b12, o2, o4, 0);
  CONV(o4, 4, bcv, (const u16*)nullptr, s2, 0);
  // attention 1: F2 = low1 + P1*low2 -> s1, F1 = low2 + P1^T*low1 -> s2
  attn_k<<<dim3(NB * NH), dim3(256), 0, stream>>>(s1, s2, o2, o1, s1, s2);
  // fe2 @ low1 -> Q2 (o1; L1T dead after skip-read)
  CONV(o1, 2, b21, (const u16*)nullptr, o3, 1);
  CONV(o3, 3, b22, o1, o4, 0);
  CONV(o4, 4, bcv, (const u16*)nullptr, o1, 0);
  // fe2 @ low2 -> K2 (o2)
  CONV(o2, 2, b21, (const u16*)nullptr, o3, 1);
  CONV(o3, 3, b22, o2, o4, 0);
  CONV(o4, 4, bcv, (const u16*)nullptr, o2, 0);
  // attention 2: left = F2 + P2*F1 -> s1, right = F1 + P2^T*F2 -> s2 (in-place, safe)
  attn_k<<<dim3(NB * NH), dim3(256), 0, stream>>>(o1, o2, s2, s1, s1, s2);
  // final bf16 NHWC -> f32 NCHW into d_out (overwrites o1..o4, all dead)
  nhwc2nchw_k<<<dim3(NB * NH), dim3(192), 0, stream>>>(s1, outL);
  nhwc2nchw_k<<<dim3(NB * NH), dim3(192), 0, stream>>>(s2, outR);
#undef CONV
}

// Round 4
// 639.285 us; speedup vs baseline: 1.4560x; 1.4560x over previous
//
#include <hip/hip_runtime.h>
#include <stdint.h>

#define NB 4
#define NC 64
#define NH 192
#define NW 192

typedef __attribute__((ext_vector_type(8))) short bf16x8;
typedef __attribute__((ext_vector_type(4))) float f32x4;
typedef unsigned short u16;
typedef unsigned int u32;

__device__ inline float bf2f(u16 x){ u32 u = ((u32)x) << 16; return __builtin_bit_cast(float, u); }
__device__ inline u16 f2bf(float f){ u32 u = __builtin_bit_cast(u32, f); u32 r = u + 0x7fffu + ((u >> 16) & 1u); return (u16)(r >> 16); }
__device__ inline bf16x8 packf8(float4 a, float4 b){
  bf16x8 r;
  r[0]=(short)f2bf(a.x); r[1]=(short)f2bf(a.y); r[2]=(short)f2bf(a.z); r[3]=(short)f2bf(a.w);
  r[4]=(short)f2bf(b.x); r[5]=(short)f2bf(b.y); r[6]=(short)f2bf(b.z); r[7]=(short)f2bf(b.w);
  return r;
}

// ---------------- weight transform: f32 OIHW [co][ci][ky][kx] -> bf16 [r][co][ci] ----------------
__global__ void wxform_k(const float* __restrict__ w0, const float* __restrict__ w1,
                         const float* __restrict__ w2, const float* __restrict__ w3,
                         const float* __restrict__ w4, u16* __restrict__ out){
  int idx = blockIdx.x * 256 + threadIdx.x;
  if (idx >= 5 * 36864) return;
  int t = idx / 36864, e = idx % 36864;
  int r = e >> 12, rem = e & 4095, co = rem >> 6, ci = rem & 63;
  const float* src = (t == 0) ? w0 : (t == 1) ? w1 : (t == 2) ? w2 : (t == 3) ? w3 : w4;
  out[idx] = f2bf(src[co * 576 + ci * 9 + r]);
}

// ---------------- f32 NCHW -> bf16 NHWC ----------------
__global__ __launch_bounds__(192) void nchw2nhwc_k(const float* __restrict__ in, u16* __restrict__ out){
  int bh = blockIdx.x; int b = bh / NH, h = bh % NH;
  int w = threadIdx.x;
  u16 v[64];
  const float* p = in + ((size_t)b * NC * NH + h) * NW + w;
#pragma unroll
  for (int c = 0; c < 64; ++c) v[c] = f2bf(p[(size_t)c * NH * NW]);
  uint4* q4 = (uint4*)(out + ((size_t)bh * NW + w) * NC);
#pragma unroll
  for (int i = 0; i < 8; ++i){
    uint4 t;
    t.x = (u32)v[i*8+0] | ((u32)v[i*8+1] << 16);
    t.y = (u32)v[i*8+2] | ((u32)v[i*8+3] << 16);
    t.z = (u32)v[i*8+4] | ((u32)v[i*8+5] << 16);
    t.w = (u32)v[i*8+6] | ((u32)v[i*8+7] << 16);
    q4[i] = t;
  }
}

// ---------------- bf16 -> f32 expand (same layout) ----------------
__global__ __launch_bounds__(256) void bf2f_k(const u16* __restrict__ in, float* __restrict__ out){
  int i = blockIdx.x * 256 + threadIdx.x;   // over BUF/8
  uint4 v = ((const uint4*)in)[i];
  float4 f0, f1;
  f0.x = bf2f((u16)(v.x & 0xffff)); f0.y = bf2f((u16)(v.x >> 16));
  f0.z = bf2f((u16)(v.y & 0xffff)); f0.w = bf2f((u16)(v.y >> 16));
  f1.x = bf2f((u16)(v.z & 0xffff)); f1.y = bf2f((u16)(v.z >> 16));
  f1.z = bf2f((u16)(v.w & 0xffff)); f1.w = bf2f((u16)(v.w >> 16));
  ((float4*)out)[2*i]   = f0;
  ((float4*)out)[2*i+1] = f1;
}

// ---------------- conv3x3 v2: 3 rows x 96 w per block, LDS ring buffer ----------------
// grid 512 = (2 w-halves) x (256 strips of 3 rows); block 256 = 4 waves (mh=co-half, wq=w-quarter)
__global__ __launch_bounds__(256) void conv3_k(const u16* __restrict__ in, const u16* __restrict__ wt,
    const float* __restrict__ bias, const u16* __restrict__ skip, u16* __restrict__ out, int relu){
  __shared__ __align__(16) u16 xr[3][98 * 72];   // stride 72: conflict-free, 42336 B total
  int blk = blockIdx.x;
  int wh = blk & 1;
  int strip = blk >> 1;
  int g0 = strip * 3;
  int b = g0 / NH, h0 = g0 % NH;        // strips never cross b (192 % 3 == 0)
  int wstart = wh * 96;
  int tid = threadIdx.x;
  int wvv = tid >> 6, lane = tid & 63, l15 = lane & 15, qd = lane >> 4;
  int mh = wvv >> 1, wq = wvv & 1;

#define STAGE(hh_) do { \
    int hh = (hh_); \
    int slot = ((hh % 3) + 3) % 3; \
    bool rowok = (hh >= 0) && (hh < NH); \
    const u16* src = in + (((size_t)b * NH + (rowok ? hh : 0)) * NW) * 64; \
    for (int k2 = tid; k2 < 784; k2 += 256){ \
      int x = k2 >> 3, part = k2 & 7; \
      int w = wstart - 1 + x; \
      uint4 val = make_uint4(0,0,0,0); \
      if (rowok && w >= 0 && w < NW) val = *(const uint4*)(src + (size_t)w * 64 + part * 8); \
      *(uint4*)&xr[slot][x * 72 + part * 8] = val; \
    } \
  } while(0)

  STAGE(h0 - 1);
  STAGE(h0);
  for (int j = 0; j < 3; ++j){
    int h = h0 + j;
    STAGE(h + 1);
    __syncthreads();
    f32x4 acc[2][3];
#pragma unroll
    for (int mt = 0; mt < 2; ++mt)
#pragma unroll
      for (int nt = 0; nt < 3; ++nt) acc[mt][nt] = (f32x4){0.f,0.f,0.f,0.f};
#pragma unroll
    for (int r = 0; r < 9; ++r){
      int ky = r / 3, kx = r % 3;
      int hs = h - 1 + ky;
      const u16* xbase = xr[((hs % 3) + 3) % 3];
#pragma unroll
      for (int ks = 0; ks < 2; ++ks){
        int ci = ks * 32 + qd * 8;
        const u16* wp = wt + r * 4096 + ci;
        bf16x8 a0 = *(const bf16x8*)(wp + (mh * 32 + l15) * 64);
        bf16x8 a1 = *(const bf16x8*)(wp + (mh * 32 + 16 + l15) * 64);
#pragma unroll
        for (int nt = 0; nt < 3; ++nt){
          int x = wq * 48 + nt * 16 + l15 + kx;
          bf16x8 bfr = *(const bf16x8*)&xr[0][0 + ((hs % 3) + 3) % 3 * 0];
          bfr = *(const bf16x8*)&xbase[x * 72 + ci];
          acc[0][nt] = __builtin_amdgcn_mfma_f32_16x16x32_bf16(a0, bfr, acc[0][nt], 0, 0, 0);
          acc[1][nt] = __builtin_amdgcn_mfma_f32_16x16x32_bf16(a1, bfr, acc[1][nt], 0, 0, 0);
        }
      }
    }
    size_t rowbase = ((size_t)(b * NH + h)) * NW * 64;
#pragma unroll
    for (int mt = 0; mt < 2; ++mt){
      int co0 = mh * 32 + mt * 16 + qd * 4;
      float4 bb = *(const float4*)(bias + co0);
#pragma unroll
      for (int nt = 0; nt < 3; ++nt){
        int w = wstart + wq * 48 + nt * 16 + l15;
        size_t o = rowbase + (size_t)w * 64 + co0;
        float v0 = acc[mt][nt][0] + bb.x, v1 = acc[mt][nt][1] + bb.y;
        float v2 = acc[mt][nt][2] + bb.z, v3 = acc[mt][nt][3] + bb.w;
        if (relu){ v0 = fmaxf(v0,0.f); v1 = fmaxf(v1,0.f); v2 = fmaxf(v2,0.f); v3 = fmaxf(v3,0.f); }
        if (skip){
          uint2 ss = *(const uint2*)(skip + o);
          v0 += bf2f((u16)(ss.x & 0xffff)); v1 += bf2f((u16)(ss.x >> 16));
          v2 += bf2f((u16)(ss.y & 0xffff)); v3 += bf2f((u16)(ss.y >> 16));
        }
        uint2 st;
        st.x = (u32)f2bf(v0) | ((u32)f2bf(v1) << 16);
        st.y = (u32)f2bf(v2) | ((u32)f2bf(v3) << 16);
        *(uint2*)(out + o) = st;
      }
    }
    __syncthreads();
  }
#undef STAGE
}

// ---------------- attention v2 ----------------
// Q,K: bf16 NHWC rows. X,Y: NCHW (f32 if XYF32 else bf16). Outputs: bf16 NCHW.
// P = softmax_rows(Q K^T); outA^T = Y^T + X^T-rows x P-rows ; outB^T = X^T + Y^T-rows x Pt-rows
template<int XYF32>
__global__ __launch_bounds__(256) void attn_k(const u16* __restrict__ Q, const u16* __restrict__ K,
    const void* __restrict__ Xv, const void* __restrict__ Yv,
    u16* __restrict__ outA, u16* __restrict__ outB){
  __shared__ __align__(16) u16 P [192 * 200];
  __shared__ __align__(16) u16 Pt[192 * 200];
  int bh = blockIdx.x, b = bh / NH, h = bh % NH;
  int tid = threadIdx.x, wv = tid >> 6, lane = tid & 63, l15 = lane & 15, qd = lane >> 4;
  size_t rowo = (size_t)bh * NW * 64;
  const u16* Qr = Q + rowo; const u16* Kr = K + rowo;
  const size_t CS = (size_t)NH * NW;              // 36864
  size_t xb0 = (size_t)b * 64 * CS + (size_t)h * NW;
  const float* Xf = (const float*)Xv; const float* Yf = (const float*)Yv;
  const u16* Xb = (const u16*)Xv; const u16* Yb = (const u16*)Yv;

  // ---- phase 1: S = Q K^T, softmax, dual-store P and Pt ----
#pragma unroll 1
  for (int mi = 0; mi < 3; ++mi){
    int mt = wv * 3 + mi;
    f32x4 s[12];
#pragma unroll
    for (int nt = 0; nt < 12; ++nt) s[nt] = (f32x4){0,0,0,0};
#pragma unroll
    for (int ks = 0; ks < 2; ++ks){
      bf16x8 aq = *(const bf16x8*)(Qr + (mt * 16 + l15) * 64 + ks * 32 + qd * 8);
#pragma unroll
      for (int nt = 0; nt < 12; ++nt){
        bf16x8 bk = *(const bf16x8*)(Kr + (nt * 16 + l15) * 64 + ks * 32 + qd * 8);
        s[nt] = __builtin_amdgcn_mfma_f32_16x16x32_bf16(aq, bk, s[nt], 0, 0, 0);
      }
    }
#pragma unroll
    for (int rg = 0; rg < 4; ++rg){
      float mx = -1e30f;
#pragma unroll
      for (int nt = 0; nt < 12; ++nt) mx = fmaxf(mx, s[nt][rg]);
      mx = fmaxf(mx, __shfl_xor(mx, 1));
      mx = fmaxf(mx, __shfl_xor(mx, 2));
      mx = fmaxf(mx, __shfl_xor(mx, 4));
      mx = fmaxf(mx, __shfl_xor(mx, 8));
      float sum = 0.f;
#pragma unroll
      for (int nt = 0; nt < 12; ++nt){ float ev = __expf(s[nt][rg] - mx); s[nt][rg] = ev; sum += ev; }
      sum += __shfl_xor(sum, 1);
      sum += __shfl_xor(sum, 2);
      sum += __shfl_xor(sum, 4);
      sum += __shfl_xor(sum, 8);
      float inv = 1.f / sum;
      int w = mt * 16 + qd * 4 + rg;
#pragma unroll
      for (int nt = 0; nt < 12; ++nt){
        float val = s[nt][rg] * inv;
        s[nt][rg] = val;                       // keep normalized for Pt pack
        P[w * 200 + nt * 16 + l15] = f2bf(val);
      }
    }
    // Pt[v][w] = P[v->row, w->col]: lane packs its 4 rg (consecutive w) per nt
#pragma unroll
    for (int nt = 0; nt < 12; ++nt){
      uint2 pk;
      pk.x = (u32)f2bf(s[nt][0]) | ((u32)f2bf(s[nt][1]) << 16);
      pk.y = (u32)f2bf(s[nt][2]) | ((u32)f2bf(s[nt][3]) << 16);
      *(uint2*)&Pt[(nt * 16 + l15) * 200 + mt * 16 + qd * 4] = pk;
    }
  }
  __syncthreads();

  // ---- phase 2: accA^T[c][w] = sum_v X^T[c][v] P[w][v]; accB^T[c][w] = sum_v Y^T[c][v] Pt[w][v]
  f32x4 accA[3][4], accB[3][4];
#pragma unroll
  for (int ni = 0; ni < 3; ++ni)
#pragma unroll
    for (int mt = 0; mt < 4; ++mt){ accA[ni][mt] = (f32x4){0,0,0,0}; accB[ni][mt] = (f32x4){0,0,0,0}; }
#pragma unroll 1
  for (int ks = 0; ks < 6; ++ks){
    int v0 = ks * 32 + qd * 8;
    bf16x8 aX[4], aY[4];
#pragma unroll
    for (int mt = 0; mt < 4; ++mt){
      int c = mt * 16 + l15;
      size_t off = xb0 + (size_t)c * CS + v0;
      if (XYF32){
        float4 x0 = *(const float4*)(Xf + off), x1 = *(const float4*)(Xf + off + 4);
        float4 y0 = *(const float4*)(Yf + off), y1 = *(const float4*)(Yf + off + 4);
        aX[mt] = packf8(x0, x1); aY[mt] = packf8(y0, y1);
      } else {
        aX[mt] = *(const bf16x8*)(Xb + off);
        aY[mt] = *(const bf16x8*)(Yb + off);
      }
    }
#pragma unroll
    for (int ni = 0; ni < 3; ++ni){
      int wrow = (wv * 3 + ni) * 16 + l15;
      bf16x8 bP  = *(const bf16x8*)&P [wrow * 200 + v0];
      bf16x8 bPt = *(const bf16x8*)&Pt[wrow * 200 + v0];
#pragma unroll
      for (int mt = 0; mt < 4; ++mt){
        accA[ni][mt] = __builtin_amdgcn_mfma_f32_16x16x32_bf16(aX[mt], bP,  accA[ni][mt], 0, 0, 0);
        accB[ni][mt] = __builtin_amdgcn_mfma_f32_16x16x32_bf16(aY[mt], bPt, accB[ni][mt], 0, 0, 0);
      }
    }
  }
  // epilogue: outA^T[c][w] += Y^T[c][w]; outB^T[c][w] += X^T[c][w]; store bf16 NCHW
#pragma unroll
  for (int ni = 0; ni < 3; ++ni){
    int w = (wv * 3 + ni) * 16 + l15;
#pragma unroll
    for (int mt = 0; mt < 4; ++mt){
#pragma unroll
      for (int rg = 0; rg < 4; ++rg){
        int c = mt * 16 + qd * 4 + rg;
        size_t o = xb0 + (size_t)c * CS + w;
        float ra = XYF32 ? Yf[o] : bf2f(Yb[o]);
        float rb = XYF32 ? Xf[o] : bf2f(Xb[o]);
        outA[o] = f2bf(accA[ni][mt][rg] + ra);
        outB[o] = f2bf(accB[ni][mt][rg] + rb);
      }
    }
  }
}

extern "C" void kernel_launch(void* const* d_in, const int* in_sizes, int n_in,
                              void* d_out, int out_size, void* d_ws, size_t ws_size,
                              hipStream_t stream){
  const float* low1 = (const float*)d_in[0];
  const float* low2 = (const float*)d_in[1];
  const float* b11 = (const float*)d_in[3];
  const float* b12 = (const float*)d_in[5];
  const float* b21 = (const float*)d_in[7];
  const float* b22 = (const float*)d_in[9];
  const float* bcv = (const float*)d_in[11];
  const size_t BUF = (size_t)NB * NH * NW * NC;   // 9437184 elements
  // ws (bf16): WT | s1 | s2  (38.1 MB, same as passing round 3)
  u16* WT = (u16*)d_ws;
  u16* s1 = WT + 184320;
  u16* s2 = s1 + BUF;
  // d_out doubles as 4 bf16 scratch slots until the final expand
  u16* o1 = (u16*)d_out;              // L1T (NHWC) -> Q2
  u16* o2 = o1 + BUF;                 // L2T (NHWC) -> K2
  u16* o3 = o1 + 2 * BUF;             // conv temp -> F2 (NCHW)
  u16* o4 = o1 + 3 * BUF;             // conv temp -> F1 (NCHW)
  float* outL = (float*)d_out;
  float* outR = outL + BUF;

  wxform_k<<<dim3(720), dim3(256), 0, stream>>>(
      (const float*)d_in[2], (const float*)d_in[4], (const float*)d_in[6],
      (const float*)d_in[8], (const float*)d_in[10], WT);
  nchw2nhwc_k<<<dim3(NB * NH), dim3(192), 0, stream>>>(low1, o1);   // L1T
  nchw2nhwc_k<<<dim3(NB * NH), dim3(192), 0, stream>>>(low2, o2);   // L2T

#define CONV(in_, wti, bias_, skip_, out_, relu_) \
  conv3_k<<<dim3(512), dim3(256), 0, stream>>>(in_, WT + (wti) * 36864, bias_, skip_, out_, relu_)

  // fe1 @ low1 -> Q1 (s1)
  CONV(o1, 0, b11, (const u16*)nullptr, o3, 1);
  CONV(o3, 1, b12, o1, o4, 0);
  CONV(o4, 4, bcv, (const u16*)nullptr, s1, 0);
  // fe1 @ low2 -> K1 (s2)
  CONV(o2, 0, b11, (const u16*)nullptr, o3, 1);
  CONV(o3, 1, b12, o2, o4, 0);
  CONV(o4, 4, bcv, (const u16*)nullptr, s2, 0);
  // attention 1 (X=low2 f32, Y=low1 f32): F2 = low1 + P1*low2 -> o3 (NCHW), F1 = low2 + P1^T*low1 -> o4
  attn_k<1><<<dim3(NB * NH), dim3(256), 0, stream>>>(s1, s2, (const void*)low2, (const void*)low1, o3, o4);
  // fe2 @ low1 -> Q2 (o1)
  CONV(o1, 2, b21, (const u16*)nullptr, s1, 1);
  CONV(s1, 3, b22, o1, s2, 0);
  CONV(s2, 4, bcv, (const u16*)nullptr, o1, 0);
  // fe2 @ low2 -> K2 (o2)
  CONV(o2, 2, b21, (const u16*)nullptr, s1, 1);
  CONV(s1, 3, b22, o2, s2, 0);
  CONV(s2, 4, bcv, (const u16*)nullptr, o2, 0);
  // attention 2 (X=F1 bf16, Y=F2 bf16): left -> s1 (NCHW bf16), right -> s2
  attn_k<0><<<dim3(NB * NH), dim3(256), 0, stream>>>(o1, o2, (const void*)o4, (const void*)o3, s1, s2);
  // expand bf16 NCHW -> f32 NCHW into d_out
  bf2f_k<<<dim3((int)(BUF / 8 / 256)), dim3(256), 0, stream>>>(s1, outL);
  bf2f_k<<<dim3((int)(BUF / 8 / 256)), dim3(256), 0, stream>>>(s2, outR);
#undef CONV
}